// Round 12
// baseline (263.216 us; speedup 1.0000x reference)
//
#include <hip/hip_runtime.h>
#include <hip/hip_bf16.h>
#include <stdint.h>

typedef int    i32x4 __attribute__((ext_vector_type(4)));
typedef unsigned char u8;

#define HD 4096   // Hadamard / K dimension (elements == bytes for int8)

// padded LDS index: +4 floats per 64 -> breaks power-of-2 bank strides
#define PAD(i) ((i) + (((i) >> 6) << 2))

#define FWHT16(v) do { \
  _Pragma("unroll") \
  for (int st = 0; st < 4; ++st) { \
    const int sg = 1 << st; \
    _Pragma("unroll") \
    for (int g = 0; g < 16; g += 2 * sg) { \
      _Pragma("unroll") \
      for (int k2 = 0; k2 < sg; ++k2) { \
        float ua = v[g + k2], ub = v[g + k2 + sg]; \
        v[g + k2] = ua + ub; \
        v[g + k2 + sg] = ua - ub; \
      } \
    } \
  } \
} while (0)

// ---------------------------------------------------------------------------
// Kernel 1: row-wise FWHT (== x @ H, Sylvester H) + act fake-quant, int8 out.
// Register radix-16, two padded-LDS exchanges. (verified R5/R6)
// ---------------------------------------------------------------------------
__global__ __launch_bounds__(256) void fwht_actq(
    const float* __restrict__ x, const float* __restrict__ alpha,
    const float* __restrict__ beta, u8* __restrict__ qx,
    float* __restrict__ Sx)
{
  __shared__ float s[PAD(4095) + 1];
  const int row = blockIdx.x;
  const int t = threadIdx.x;
  const float* xin = x + (size_t)row * HD;
  float v[16];

  // Round A: bits 8-11 (idx = t + 256j), coalesced scalar loads
  #pragma unroll
  for (int j = 0; j < 16; ++j) v[j] = xin[t + 256 * j];
  FWHT16(v);
  #pragma unroll
  for (int j = 0; j < 16; ++j) { int i0 = t + 256 * j; s[PAD(i0)] = v[j]; }
  __syncthreads();

  // Round B: bits 4-7 (idx = b + 16j + 256c, b=t&15, c=t>>4)
  const int bb = t & 15, cc = t >> 4;
  #pragma unroll
  for (int j = 0; j < 16; ++j) { int i0 = bb + 16 * j + 256 * cc; v[j] = s[PAD(i0)]; }
  FWHT16(v);
  #pragma unroll
  for (int j = 0; j < 16; ++j) { int i0 = bb + 16 * j + 256 * cc; s[PAD(i0)] = v[j]; }
  __syncthreads();

  // Round C: bits 0-3 (idx = 16t + j) -- 16 consecutive, PAD-contiguous
  {
    const float4* p4 = (const float4*)&s[16 * t + ((t >> 2) << 2)];
    #pragma unroll
    for (int q = 0; q < 4; ++q) {
      float4 f = p4[q];
      v[q * 4 + 0] = f.x; v[q * 4 + 1] = f.y; v[q * 4 + 2] = f.z; v[q * 4 + 3] = f.w;
    }
  }
  FWHT16(v);

  // quant: q = rint(clip((xr/64 + beta)/alpha, -8, 7)), pack 16 x int8
  const float al = alpha[0];
  const float be = beta[0];
  float qsum = 0.f;
  int pk[4];
  #pragma unroll
  for (int c4 = 0; c4 < 4; ++c4) {
    int w32 = 0;
    #pragma unroll
    for (int k = 0; k < 4; ++k) {
      float xv = v[c4 * 4 + k] * 0.015625f + be;
      float tq = xv / al;
      tq = fminf(fmaxf(tq, -8.f), 7.f);
      float qq = rintf(tq);                // half-to-even == np.round
      qsum += qq;
      w32 |= ((int)qq & 0xFF) << (k * 8);
    }
    pk[c4] = w32;
  }
  *(int4*)(qx + (size_t)row * HD + 16 * t) = make_int4(pk[0], pk[1], pk[2], pk[3]);

  __syncthreads();
  s[t] = qsum;
  __syncthreads();
  for (int o = 128; o > 0; o >>= 1) {
    if (t < o) s[t] += s[t + o];
    __syncthreads();
  }
  if (t == 0) Sx[row] = s[0];
}

// ---------------------------------------------------------------------------
// Kernel 2: weight fake-quant (learnable-threshold quantizer, forward path)
// ---------------------------------------------------------------------------
__global__ __launch_bounds__(256) void wq_kernel(
    const float* __restrict__ w, const float* __restrict__ alpha,
    const float* __restrict__ beta, const float* __restrict__ a_w,
    u8* __restrict__ qw, float* __restrict__ Sw)
{
  __shared__ float red[256];
  const int row = blockIdx.x;
  const int t = threadIdx.x;
  const float al = alpha[0];
  const float be = beta[0];
  float th[15];
  #pragma unroll
  for (int i = 0; i < 15; ++i) th[i] = 0.5f * (a_w[i] + a_w[i + 1]);

  float qsum = 0.f;
  int* qw32 = (int*)(qw + (size_t)row * HD);
  #pragma unroll
  for (int c = 0; c < 4; ++c) {
    int e = c * 1024 + t * 4;
    float4 v = *(const float4*)(w + (size_t)row * HD + e);
    float vv[4] = {v.x, v.y, v.z, v.w};
    int pk = 0;
    #pragma unroll
    for (int k = 0; k < 4; ++k) {
      float xv = vv[k] + be;
      float tq = xv / al;
      tq = fminf(fmaxf(tq, -8.f), 7.f);
      float qq = -8.f;
      #pragma unroll
      for (int i = 0; i < 15; ++i) qq = (tq > th[i]) ? (float)(i - 7) : qq;
      qsum += qq;
      pk |= ((int)qq & 0xFF) << (k * 8);
    }
    qw32[c * 256 + t] = pk;
  }

  red[t] = qsum;
  __syncthreads();
  for (int o = 128; o > 0; o >>= 1) {
    if (t < o) red[t] += red[t + o];
    __syncthreads();
  }
  if (t == 0) Sw[row] = red[0];
}

// ---------------------------------------------------------------------------
// Kernel 3: 256x128-tile INT8 MFMA GEMM, 2 INDEPENDENT blocks/CU.
//   Thesis: R4's 35% MfmaUtil = lockstep serialization (read window and
//   MFMA window alternate under one barrier group). Split the CU into TWO
//   barrier domains that desync: block = 256x128, 4 waves (2M x 2N),
//   wave tile stays 128x64 (R4's LDS/MFMA balance -- R10's failure was
//   shrinking this), BK=64, LDS 48 KiB -> 2 blocks/CU, acc=128 regs fits
//   256/wave budget at launch_bounds(256,2) (R5's spill excluded).
//   Per-CU totals (MFMA ops, LDS bytes/op, stage bytes) == R4; only the
//   sync topology changes.
//   Sync skeleton = R5/R10-verified 2-phase:
//     ph0: read B(4)+A-ch0(4) | STAGE_A(t+1) | bar | lgkm0 | 16 MFMA | bar
//     ph1: read A-ch1(4)      | STAGE_B(t+1) | bar | lgkm0 | 16 MFMA |
//          vmcnt(0) | bar
//   Full vmcnt(0) drain once/tile before the closing barrier -> every
//   wave's stages confirmed workgroup-wide before any t+1 read (the R8
//   cross-wave race class is structurally excluded).
//   Chunk swizzle per 16 KiB A region (256 rows x 4 kc of 16B) and 8 KiB
//   B region (128 rows x 4 kc): chunk(row,kc) at (row>>3)*32+kc*8+(row&7)
//   (same formula as R4) -> conflict-free ds_read_b128. Staging source
//   pre-permuted: chunk c=j*256+wv*64+lane -> row=(c>>5)*8+(c&7),
//   kc=(c>>3)&3 (spot-checked bijective).
// ---------------------------------------------------------------------------
#define ABUF(buf) ((buf) * 16384)            // A: [0, 32K)
#define BBUF(buf) (32768 + (buf) * 8192)     // B: [32K, 48K)

__device__ __forceinline__ void gload_lds16(const void* g, void* l) {
  __builtin_amdgcn_global_load_lds(
      (__attribute__((address_space(1))) void*)((void*)g),
      (__attribute__((address_space(3))) void*)(l), 16, 0, 0);
}

// stage A tile of K-tile u into buf: 256 rows x 64 B = 16 KiB = 4 gloads/wave
#define STAGE_A(buf, u) do { \
  _Pragma("unroll") \
  for (int j = 0; j < 4; ++j) \
    gload_lds16(gA + (size_t)j * 64 * 4096 + (size_t)(u) * 64, \
                &lds[ABUF(buf) + j * 4096 + wv * 1024]); \
} while (0)

// stage B tile: 128 rows x 64 B = 8 KiB = 2 gloads/wave
#define STAGE_B(buf, u) do { \
  _Pragma("unroll") \
  for (int j = 0; j < 2; ++j) \
    gload_lds16(gB + (size_t)j * 64 * 4096 + (size_t)(u) * 64, \
                &lds[BBUF(buf) + j * 4096 + wv * 1024]); \
} while (0)

#define CPWAIT(n) asm volatile("s_waitcnt vmcnt(" #n ")" ::: "memory")
#define NOSTMT ((void)0)

// ph0: B frags + A-ch0 frags from buf p, stage A(t+1), 16 MFMA -> acc[0..3]
#define PHASE0(p, STAGE_STMT) do { \
  _Pragma("unroll") \
  for (int n = 0; n < 4; ++n) \
    b[n] = *(const i32x4*)&lds[BBUF(p) + posB[n]]; \
  _Pragma("unroll") \
  for (int i = 0; i < 4; ++i) \
    a[i] = *(const i32x4*)&lds[ABUF(p) + posA[i]]; \
  STAGE_STMT; \
  __builtin_amdgcn_sched_barrier(0); \
  __builtin_amdgcn_s_barrier(); \
  asm volatile("s_waitcnt lgkmcnt(0)" ::: "memory"); \
  __builtin_amdgcn_sched_barrier(0); \
  __builtin_amdgcn_s_setprio(1); \
  _Pragma("unroll") \
  for (int i = 0; i < 4; ++i) { \
    _Pragma("unroll") \
    for (int n = 0; n < 4; ++n) \
      acc[i][n] = __builtin_amdgcn_mfma_i32_16x16x64_i8(a[i], b[n], acc[i][n], 0, 0, 0); \
  } \
  __builtin_amdgcn_s_setprio(0); \
  __builtin_amdgcn_sched_barrier(0); \
  __builtin_amdgcn_s_barrier(); \
  __builtin_amdgcn_sched_barrier(0); \
} while (0)

// ph1: A-ch1 frags from buf p, stage B(t+1), 16 MFMA -> acc[4..7], drain
#define PHASE1(p, STAGE_STMT, CP_STMT) do { \
  _Pragma("unroll") \
  for (int i = 0; i < 4; ++i) \
    a[i] = *(const i32x4*)&lds[ABUF(p) + posA[4 + i]]; \
  STAGE_STMT; \
  __builtin_amdgcn_sched_barrier(0); \
  __builtin_amdgcn_s_barrier(); \
  asm volatile("s_waitcnt lgkmcnt(0)" ::: "memory"); \
  __builtin_amdgcn_sched_barrier(0); \
  __builtin_amdgcn_s_setprio(1); \
  _Pragma("unroll") \
  for (int i = 0; i < 4; ++i) { \
    _Pragma("unroll") \
    for (int n = 0; n < 4; ++n) \
      acc[4 + i][n] = __builtin_amdgcn_mfma_i32_16x16x64_i8(a[i], b[n], acc[4 + i][n], 0, 0, 0); \
  } \
  __builtin_amdgcn_s_setprio(0); \
  __builtin_amdgcn_sched_barrier(0); \
  CP_STMT; \
  __builtin_amdgcn_s_barrier(); \
  __builtin_amdgcn_sched_barrier(0); \
} while (0)

// one K-tile (read buf p), staging tile t+1 into buf 1-p
#define TILEBODY(p, t) do { \
  PHASE0(p, STAGE_A(1-(p), (t)+1)); \
  PHASE1(p, STAGE_B(1-(p), (t)+1), CPWAIT(0)); \
} while (0)

#define TILELAST(p) do { \
  PHASE0(p, NOSTMT); \
  PHASE1(p, NOSTMT, NOSTMT); \
} while (0)

__global__ __launch_bounds__(256, 2) void gemm_qq(
    const u8* __restrict__ qx, const u8* __restrict__ qw,
    const float* __restrict__ bias, const float* __restrict__ Sx,
    const float* __restrict__ Sw,
    const float* __restrict__ p_aa, const float* __restrict__ p_ba,
    const float* __restrict__ p_aw, const float* __restrict__ p_bw,
    float* __restrict__ out, int M, int N, int K)
{
  __shared__ u8 lds[49152];   // 48 KiB -> 2 blocks/CU (VGPR-limited, no spill)
  const int tid  = threadIdx.x;
  const int lane = tid & 63;
  const int wv   = tid >> 6;       // wave 0..3
  const int wm   = wv >> 1;        // 0..1 (M half of 256: 128 rows)
  const int wn   = wv & 1;         // 0..1 (N half of 128: 64 cols)

  // T1: bijective XCD swizzle (1024 blocks, 8 XCDs, 128 per XCD)
  const int bid  = blockIdx.x;
  const int wgid = (bid & 7) * 128 + (bid >> 3);
  const int bm   = wgid >> 5;      // 0..31  (M/256)
  const int bn   = wgid & 31;      // 0..31  (N/128)

  // frag read byte-positions, chunk-permuted (chunk = 16B):
  // chunk(row, kc=lane>>4) at idx (row>>3)*32 + kc*8 + (row&7)
  int posA[8], posB[4];
  #pragma unroll
  for (int fm = 0; fm < 8; ++fm) {
    int row = wm * 128 + fm * 16 + (lane & 15);
    posA[fm] = (((row >> 3) * 32) + (lane >> 4) * 8 + (row & 7)) * 16;
  }
  #pragma unroll
  for (int n = 0; n < 4; ++n) {
    int col = wn * 64 + n * 16 + (lane & 15);
    posB[n] = (((col >> 3) * 32) + (lane >> 4) * 8 + (col & 7)) * 16;
  }

  // staging sources, pre-permuted so linear gload_lds dest lands swizzled:
  // chunk c = j*256 + wv*64 + lane -> row = (c>>5)*8+(c&7) = j*64 + rs,
  // kc = (c>>3)&3 = (lane>>3)&3, with rs = wv*16 + ((lane>>5))*8 + (lane&7)
  const int rs  = wv * 16 + ((lane >> 5) << 3) + (lane & 7);
  const int kcs = ((lane >> 3) & 3) * 16;
  const u8* gA = qx + (size_t)(bm * 256 + rs) * K + kcs;
  const u8* gB = qw + (size_t)(bn * 128 + rs) * K + kcs;

  i32x4 acc[8][4] = {};
  i32x4 a[4], b[4];

  // prologue: stage tile 0 into buf 0
  STAGE_A(0, 0);
  STAGE_B(0, 0);
  CPWAIT(0);
  __builtin_amdgcn_sched_barrier(0);
  __builtin_amdgcn_s_barrier();
  __builtin_amdgcn_sched_barrier(0);

  // main loop: 64 K-tiles (K = 4096 bytes, BK = 64)
  for (int t = 0; t < 62; t += 2) {
    TILEBODY(0, t);
    TILEBODY(1, t + 1);
  }
  TILEBODY(0, 62);
  TILELAST(1);

  // epilogue: out = aa*aw*S - aa*bw*Sx[m] - aw*ba*Sw[n] + K*ba*bw + bias[n]
  const float aa = p_aa[0], ba = p_ba[0], aw = p_aw[0], bw = p_bw[0];
  const float scale  = aa * aw;
  const float rowmul = -aa * bw;
  const float colmul = -aw * ba;
  const float cterm  = (float)K * ba * bw;

  #pragma unroll
  for (int n = 0; n < 4; ++n) {
    const int col = bn * 128 + wn * 64 + n * 16 + (lane & 15);
    const float colc = bias[col] + colmul * Sw[col] + cterm;
    #pragma unroll
    for (int fm = 0; fm < 8; ++fm) {
      const int row0 = bm * 256 + wm * 128 + fm * 16 + ((lane >> 4) << 2);
      #pragma unroll
      for (int j2 = 0; j2 < 4; ++j2) {
        const int row = row0 + j2;
        out[(size_t)row * N + col] = (float)acc[fm][n][j2] * scale + rowmul * Sx[row] + colc;
      }
    }
  }
}

// ---------------------------------------------------------------------------
extern "C" void kernel_launch(void* const* d_in, const int* in_sizes, int n_in,
                              void* d_out, int out_size, void* d_ws, size_t ws_size,
                              hipStream_t stream) {
  const float* x       = (const float*)d_in[0];
  const float* wgt     = (const float*)d_in[1];
  const float* bias    = (const float*)d_in[2];
  const float* alpha_a = (const float*)d_in[3];
  const float* beta_a  = (const float*)d_in[4];
  const float* alpha_w = (const float*)d_in[5];
  const float* beta_w  = (const float*)d_in[6];
  const float* a_w     = (const float*)d_in[7];

  const int K = HD;                 // 4096
  const int M = in_sizes[0] / K;    // 8192
  const int N = in_sizes[1] / K;    // 4096

  char* ws = (char*)d_ws;
  u8* qx = (u8*)ws;                                   // M*K int8
  u8* qw = (u8*)(ws + (size_t)M * K);                 // N*K int8
  float* Sx = (float*)(ws + (size_t)M * K + (size_t)N * K);
  float* Sw = Sx + M;

  fwht_actq<<<M, 256, 0, stream>>>(x, alpha_a, beta_a, qx, Sx);
  wq_kernel<<<N, 256, 0, stream>>>(wgt, alpha_w, beta_w, a_w, qw, Sw);

  const int nwg = (N / 128) * (M / 256);   // 32 * 32 = 1024, divisible by 8
  gemm_qq<<<nwg, 256, 0, stream>>>(qx, qw, bias, Sx, Sw,
                                   alpha_a, beta_a, alpha_w, beta_w,
                                   (float*)d_out, M, N, K);
}

// Round 13
// 215.403 us; speedup vs baseline: 1.2220x; 1.2220x over previous
//
#include <hip/hip_runtime.h>
#include <hip/hip_bf16.h>
#include <stdint.h>

typedef int    i32x4 __attribute__((ext_vector_type(4)));
typedef unsigned char u8;

#define HD 4096   // Hadamard / K dimension (elements == bytes for int8)

// padded LDS index: +4 floats per 64 -> breaks power-of-2 bank strides
#define PAD(i) ((i) + (((i) >> 6) << 2))

#define FWHT16(v) do { \
  _Pragma("unroll") \
  for (int st = 0; st < 4; ++st) { \
    const int sg = 1 << st; \
    _Pragma("unroll") \
    for (int g = 0; g < 16; g += 2 * sg) { \
      _Pragma("unroll") \
      for (int k2 = 0; k2 < sg; ++k2) { \
        float ua = v[g + k2], ub = v[g + k2 + sg]; \
        v[g + k2] = ua + ub; \
        v[g + k2 + sg] = ua - ub; \
      } \
    } \
  } \
} while (0)

// ---------------------------------------------------------------------------
// Kernel 1: row-wise FWHT (== x @ H, Sylvester H) + act fake-quant, int8 out.
// Register radix-16, two padded-LDS exchanges. (verified R5/R6/R11)
// ---------------------------------------------------------------------------
__global__ __launch_bounds__(256) void fwht_actq(
    const float* __restrict__ x, const float* __restrict__ alpha,
    const float* __restrict__ beta, u8* __restrict__ qx,
    float* __restrict__ Sx)
{
  __shared__ float s[PAD(4095) + 1];
  const int row = blockIdx.x;
  const int t = threadIdx.x;
  const float* xin = x + (size_t)row * HD;
  float v[16];

  // Round A: bits 8-11 (idx = t + 256j), coalesced scalar loads
  #pragma unroll
  for (int j = 0; j < 16; ++j) v[j] = xin[t + 256 * j];
  FWHT16(v);
  #pragma unroll
  for (int j = 0; j < 16; ++j) { int i0 = t + 256 * j; s[PAD(i0)] = v[j]; }
  __syncthreads();

  // Round B: bits 4-7 (idx = b + 16j + 256c, b=t&15, c=t>>4)
  const int bb = t & 15, cc = t >> 4;
  #pragma unroll
  for (int j = 0; j < 16; ++j) { int i0 = bb + 16 * j + 256 * cc; v[j] = s[PAD(i0)]; }
  FWHT16(v);
  #pragma unroll
  for (int j = 0; j < 16; ++j) { int i0 = bb + 16 * j + 256 * cc; s[PAD(i0)] = v[j]; }
  __syncthreads();

  // Round C: bits 0-3 (idx = 16t + j) -- 16 consecutive, PAD-contiguous
  {
    const float4* p4 = (const float4*)&s[16 * t + ((t >> 2) << 2)];
    #pragma unroll
    for (int q = 0; q < 4; ++q) {
      float4 f = p4[q];
      v[q * 4 + 0] = f.x; v[q * 4 + 1] = f.y; v[q * 4 + 2] = f.z; v[q * 4 + 3] = f.w;
    }
  }
  FWHT16(v);

  // quant: q = rint(clip((xr/64 + beta)/alpha, -8, 7)), pack 16 x int8
  const float al = alpha[0];
  const float be = beta[0];
  float qsum = 0.f;
  int pk[4];
  #pragma unroll
  for (int c4 = 0; c4 < 4; ++c4) {
    int w32 = 0;
    #pragma unroll
    for (int k = 0; k < 4; ++k) {
      float xv = v[c4 * 4 + k] * 0.015625f + be;
      float tq = xv / al;
      tq = fminf(fmaxf(tq, -8.f), 7.f);
      float qq = rintf(tq);                // half-to-even == np.round
      qsum += qq;
      w32 |= ((int)qq & 0xFF) << (k * 8);
    }
    pk[c4] = w32;
  }
  *(int4*)(qx + (size_t)row * HD + 16 * t) = make_int4(pk[0], pk[1], pk[2], pk[3]);

  __syncthreads();
  s[t] = qsum;
  __syncthreads();
  for (int o = 128; o > 0; o >>= 1) {
    if (t < o) s[t] += s[t + o];
    __syncthreads();
  }
  if (t == 0) Sx[row] = s[0];
}

// ---------------------------------------------------------------------------
// Kernel 2: weight fake-quant (learnable-threshold quantizer, forward path)
// ---------------------------------------------------------------------------
__global__ __launch_bounds__(256) void wq_kernel(
    const float* __restrict__ w, const float* __restrict__ alpha,
    const float* __restrict__ beta, const float* __restrict__ a_w,
    u8* __restrict__ qw, float* __restrict__ Sw)
{
  __shared__ float red[256];
  const int row = blockIdx.x;
  const int t = threadIdx.x;
  const float al = alpha[0];
  const float be = beta[0];
  float th[15];
  #pragma unroll
  for (int i = 0; i < 15; ++i) th[i] = 0.5f * (a_w[i] + a_w[i + 1]);

  float qsum = 0.f;
  int* qw32 = (int*)(qw + (size_t)row * HD);
  #pragma unroll
  for (int c = 0; c < 4; ++c) {
    int e = c * 1024 + t * 4;
    float4 v = *(const float4*)(w + (size_t)row * HD + e);
    float vv[4] = {v.x, v.y, v.z, v.w};
    int pk = 0;
    #pragma unroll
    for (int k = 0; k < 4; ++k) {
      float xv = vv[k] + be;
      float tq = xv / al;
      tq = fminf(fmaxf(tq, -8.f), 7.f);
      float qq = -8.f;
      #pragma unroll
      for (int i = 0; i < 15; ++i) qq = (tq > th[i]) ? (float)(i - 7) : qq;
      qsum += qq;
      pk |= ((int)qq & 0xFF) << (k * 8);
    }
    qw32[c * 256 + t] = pk;
  }

  red[t] = qsum;
  __syncthreads();
  for (int o = 128; o > 0; o >>= 1) {
    if (t < o) red[t] += red[t + o];
    __syncthreads();
  }
  if (t == 0) Sw[row] = red[0];
}

// ---------------------------------------------------------------------------
// Kernel 3: 256x256 8-phase pipelined INT8 MFMA GEMM (exact q math).
//   VERIFIED OPTIMUM of the barrier-synchronized gload_lds framework
//   (R4/R6/R11: 168us GEMM = 1636 TOPS = 41% of i8 ubench ceiling).
//   BK=128 bytes (2 k-halves of 64), 8 waves (2M x 4N), 128 KiB LDS,
//   2 K-tile dbuf, mfma_i32_16x16x64_i8, 1 block/CU.
//   Phase = {ds_read frags | stage 1 half-tile | barrier | lgkm0 |
//            setprio(1) 16 MFMA setprio(0) | [vmcnt(4)] | barrier}
//   LDS chunk permutation per (buf,kh) 16KiB region: 16B chunk (row,kc) at
//   pos (row>>3)*32 + kc*8 + (row&7) -> conflict-free ds_read_b128;
//   global source pre-permuted (gload_lds dest stays linear).
//   CLOSED EXPERIMENT MATRIX (R3-R12) -- every axis pinned by a failure:
//   - bigger wave tile / 2 blocks at 256^2: acc=128 regs, spill (R5: 9x).
//   - smaller wave tile (64x64): LDS B/MFMA 384->512, LDS-bound (R10).
//   - phase merge: exposed lgkm drain scales with reads/phase (R7).
//   - frag pre-issue: no reg headroom (R9) / cross-wave vmcnt race (R8:
//     vmcnt is per-wave, staging is distributed; confirmation requires
//     own-CPWAIT + subsequent all-waves barrier).
//   - split barrier domains, same totals: phase-lock + fewer waves/domain
//     (R12: +32%).
//   - 1-barrier-per-tile: races (R3); cannot race-screen headlessly.
//   Remaining ~2x needs AITER-style asm interleave (counted vmcnt never 0,
//   no per-phase barrier) -- outside this session's verification scope.
// ---------------------------------------------------------------------------
#define LDS_BOFF 65536   // byte offset of B region (A: [0,64K), B: [64K,128K))

__device__ __forceinline__ void gload_lds16(const void* g, void* l) {
  __builtin_amdgcn_global_load_lds(
      (__attribute__((address_space(1))) void*)((void*)g),
      (__attribute__((address_space(3))) void*)(l), 16, 0, 0);
}

// stage one (buf, kh) A half-tile: 256 rows x 64 k-bytes = 16 KiB = 2 gloads
#define STAGE_A(buf, u, kh) do { \
  gload_lds16(gA0 + (size_t)(u) * 128 + (kh) * 64, &lds[(buf)*32768 + (kh)*16384 + wv*1024]); \
  gload_lds16(gA1 + (size_t)(u) * 128 + (kh) * 64, &lds[(buf)*32768 + (kh)*16384 + 8192 + wv*1024]); \
} while (0)

#define STAGE_B(buf, u, kh) do { \
  gload_lds16(gB0 + (size_t)(u) * 128 + (kh) * 64, &lds[LDS_BOFF + (buf)*32768 + (kh)*16384 + wv*1024]); \
  gload_lds16(gB1 + (size_t)(u) * 128 + (kh) * 64, &lds[LDS_BOFF + (buf)*32768 + (kh)*16384 + 8192 + wv*1024]); \
} while (0)

#define CPWAIT(n) asm volatile("s_waitcnt vmcnt(" #n ")" ::: "memory")
#define NOSTMT ((void)0)

#define PHASE(p, kk, ch, STAGE_STMT, CP_STMT) do { \
  if ((ch) == 0) { \
    _Pragma("unroll") \
    for (int n = 0; n < 4; ++n) \
      b[n] = *(const i32x4*)&lds[LDS_BOFF + (p)*32768 + (kk)*16384 + posB[n]]; \
  } \
  _Pragma("unroll") \
  for (int i = 0; i < 4; ++i) \
    a[i] = *(const i32x4*)&lds[(p)*32768 + (kk)*16384 + posA[(ch)*4 + i]]; \
  STAGE_STMT; \
  __builtin_amdgcn_sched_barrier(0); \
  __builtin_amdgcn_s_barrier(); \
  asm volatile("s_waitcnt lgkmcnt(0)" ::: "memory"); \
  __builtin_amdgcn_sched_barrier(0); \
  __builtin_amdgcn_s_setprio(1); \
  _Pragma("unroll") \
  for (int i = 0; i < 4; ++i) { \
    _Pragma("unroll") \
    for (int n = 0; n < 4; ++n) \
      acc[(ch)*4 + i][n] = __builtin_amdgcn_mfma_i32_16x16x64_i8(a[i], b[n], acc[(ch)*4 + i][n], 0, 0, 0); \
  } \
  __builtin_amdgcn_s_setprio(0); \
  __builtin_amdgcn_sched_barrier(0); \
  CP_STMT; \
  __builtin_amdgcn_s_barrier(); \
  __builtin_amdgcn_sched_barrier(0); \
} while (0)

// 4 phases of one K-tile (buf p), staging tile t+1 into buf 1-p.
#define TILEBODY(p, t) do { \
  PHASE(p, 0, 0, STAGE_A(1-(p), (t)+1, 0), NOSTMT); \
  PHASE(p, 0, 1, STAGE_B(1-(p), (t)+1, 0), CPWAIT(4)); \
  PHASE(p, 1, 0, STAGE_A(1-(p), (t)+1, 1), NOSTMT); \
  PHASE(p, 1, 1, STAGE_B(1-(p), (t)+1, 1), CPWAIT(4)); \
} while (0)

#define TILELAST(p) do { \
  PHASE(p, 0, 0, NOSTMT, NOSTMT); \
  PHASE(p, 0, 1, NOSTMT, CPWAIT(0)); \
  PHASE(p, 1, 0, NOSTMT, NOSTMT); \
  PHASE(p, 1, 1, NOSTMT, NOSTMT); \
} while (0)

__global__ __launch_bounds__(512, 2) void gemm_qq(
    const u8* __restrict__ qx, const u8* __restrict__ qw,
    const float* __restrict__ bias, const float* __restrict__ Sx,
    const float* __restrict__ Sw,
    const float* __restrict__ p_aa, const float* __restrict__ p_ba,
    const float* __restrict__ p_aw, const float* __restrict__ p_bw,
    float* __restrict__ out, int M, int N, int K)
{
  __shared__ u8 lds[131072];   // 128 KiB
  const int tid  = threadIdx.x;
  const int lane = tid & 63;
  const int wv   = tid >> 6;       // wave 0..7
  const int wm   = wv >> 2;        // 0..1 (M half)
  const int wn   = wv & 3;         // 0..3 (N quarter)

  // T1: bijective XCD swizzle (512 blocks, 8 XCDs, 64 per XCD)
  const int bid  = blockIdx.x;
  const int wgid = (bid & 7) * 64 + (bid >> 3);
  const int bm   = wgid >> 4;      // 0..31
  const int bn   = wgid & 15;      // 0..15

  // frag read byte-positions within one (buf,kh) 16KiB region, chunk-permuted:
  // frag (row, kc=lane>>4) at chunk pos (row>>3)*32 + kc*8 + (row&7)
  int posA[8], posB[4];
  #pragma unroll
  for (int fm = 0; fm < 8; ++fm) {
    int row = wm * 128 + fm * 16 + (lane & 15);
    posA[fm] = (((row >> 3) * 32) + (lane >> 4) * 8 + (row & 7)) * 16;
  }
  #pragma unroll
  for (int n = 0; n < 4; ++n) {
    int col = wn * 64 + n * 16 + (lane & 15);
    posB[n] = (((col >> 3) * 32) + (lane >> 4) * 8 + (col & 7)) * 16;
  }

  // staging global sources, pre-permuted so linear gload_lds dest lands
  // swizzled: set j chunk c=j*512+tid -> row = j*128+(tid>>5)*8+(tid&7),
  // kc = (tid>>3)&3  (16B at byte offset row*K + kh*64 + kc*16)
  const int rs0 = (tid >> 5) * 8 + (tid & 7);
  const int rs1 = 128 + rs0;
  const int kcs = ((tid >> 3) & 3) * 16;
  const u8* gA0 = qx + (size_t)(bm * 256 + rs0) * K + kcs;
  const u8* gA1 = qx + (size_t)(bm * 256 + rs1) * K + kcs;
  const u8* gB0 = qw + (size_t)(bn * 256 + rs0) * K + kcs;
  const u8* gB1 = qw + (size_t)(bn * 256 + rs1) * K + kcs;

  i32x4 acc[8][4] = {};
  i32x4 a[4], b[4];

  // prologue: stage all 4 halves of tile 0 (Ak0, Bk0, Ak1, Bk1)
  STAGE_A(0, 0, 0);
  STAGE_B(0, 0, 0);
  STAGE_A(0, 0, 1);
  STAGE_B(0, 0, 1);
  CPWAIT(4);                       // k-half0 of tile 0 landed
  __builtin_amdgcn_sched_barrier(0);
  __builtin_amdgcn_s_barrier();
  __builtin_amdgcn_sched_barrier(0);

  // main loop: 32 K-tiles (K = 4096 bytes, BK = 128)
  for (int t = 0; t < 30; t += 2) {
    TILEBODY(0, t);
    TILEBODY(1, t + 1);
  }
  TILEBODY(0, 30);
  TILELAST(1);

  // epilogue: out = aa*aw*S - aa*bw*Sx[m] - aw*ba*Sw[n] + K*ba*bw + bias[n]
  const float aa = p_aa[0], ba = p_ba[0], aw = p_aw[0], bw = p_bw[0];
  const float scale  = aa * aw;
  const float rowmul = -aa * bw;
  const float colmul = -aw * ba;
  const float cterm  = (float)K * ba * bw;

  #pragma unroll
  for (int n = 0; n < 4; ++n) {
    const int col = bn * 256 + wn * 64 + n * 16 + (lane & 15);
    const float colc = bias[col] + colmul * Sw[col] + cterm;
    #pragma unroll
    for (int fm = 0; fm < 8; ++fm) {
      const int row0 = bm * 256 + wm * 128 + fm * 16 + ((lane >> 4) << 2);
      #pragma unroll
      for (int j2 = 0; j2 < 4; ++j2) {
        const int row = row0 + j2;
        out[(size_t)row * N + col] = (float)acc[fm][n][j2] * scale + rowmul * Sx[row] + colc;
      }
    }
  }
}

// ---------------------------------------------------------------------------
extern "C" void kernel_launch(void* const* d_in, const int* in_sizes, int n_in,
                              void* d_out, int out_size, void* d_ws, size_t ws_size,
                              hipStream_t stream) {
  const float* x       = (const float*)d_in[0];
  const float* wgt     = (const float*)d_in[1];
  const float* bias    = (const float*)d_in[2];
  const float* alpha_a = (const float*)d_in[3];
  const float* beta_a  = (const float*)d_in[4];
  const float* alpha_w = (const float*)d_in[5];
  const float* beta_w  = (const float*)d_in[6];
  const float* a_w     = (const float*)d_in[7];

  const int K = HD;                 // 4096
  const int M = in_sizes[0] / K;    // 8192
  const int N = in_sizes[1] / K;    // 4096

  char* ws = (char*)d_ws;
  u8* qx = (u8*)ws;                                   // M*K int8
  u8* qw = (u8*)(ws + (size_t)M * K);                 // N*K int8
  float* Sx = (float*)(ws + (size_t)M * K + (size_t)N * K);
  float* Sw = Sx + M;

  fwht_actq<<<M, 256, 0, stream>>>(x, alpha_a, beta_a, qx, Sx);
  wq_kernel<<<N, 256, 0, stream>>>(wgt, alpha_w, beta_w, a_w, qw, Sw);

  const int nwg = (N / 256) * (M / 256);   // 16 * 32 = 512, divisible by 8
  gemm_qq<<<nwg, 512, 0, stream>>>(qx, qw, bias, Sx, Sw,
                                   alpha_a, beta_a, alpha_w, beta_w,
                                   (float*)d_out, M, N, K);
}